// Round 1
// baseline (360.498 us; speedup 1.0000x reference)
//
#include <hip/hip_runtime.h>

// loss = mean((y1/||y1||_row - y1)^2), y1: [N=4e6, D=16] fp32, yinds unused.
// (w - y)^2 = y^2 * (1/||y|| - 1)^2  -> per-lane local sumsq * (rnorm-1)^2.
// Layout: lane handles one float4; 4 consecutive lanes = one row of 16 floats.

__global__ __launch_bounds__(256) void mll_reduce_kernel(
    const float* __restrict__ y1, double* __restrict__ acc, int total4) {
    const int tid    = blockIdx.x * blockDim.x + threadIdx.x;
    const int stride = gridDim.x * blockDim.x;  // multiple of 4 -> quad-aligned

    float psum = 0.0f;
    const float4* __restrict__ y4 = reinterpret_cast<const float4*>(y1);
    for (int idx = tid; idx < total4; idx += stride) {
        const float4 v = y4[idx];
        const float local = v.x * v.x + v.y * v.y + v.z * v.z + v.w * v.w;
        // row sum of squares across the 4 lanes of this quad (D=16)
        float row = local;
        row += __shfl_xor(row, 1);
        row += __shfl_xor(row, 2);
        const float c = 1.0f / sqrtf(row) - 1.0f;  // (1/norm - 1)
        psum += local * c * c;                     // sum of (w-y)^2 for 4 elems
    }

    // wave64 butterfly reduction
    #pragma unroll
    for (int off = 32; off > 0; off >>= 1)
        psum += __shfl_xor(psum, off);

    __shared__ float wsum[4];  // 256 threads = 4 waves
    const int lane = threadIdx.x & 63;
    const int wave = threadIdx.x >> 6;
    if (lane == 0) wsum[wave] = psum;
    __syncthreads();
    if (threadIdx.x == 0) {
        const float s = wsum[0] + wsum[1] + wsum[2] + wsum[3];
        atomicAdd(acc, (double)s);  // 4096 atomics total -> negligible
    }
}

__global__ void mll_finalize_kernel(const double* __restrict__ acc,
                                    float* __restrict__ out, double inv_m) {
    out[0] = (float)(acc[0] * inv_m);  // LAMBDA1 == 1.0
}

extern "C" void kernel_launch(void* const* d_in, const int* in_sizes, int n_in,
                              void* d_out, int out_size, void* d_ws, size_t ws_size,
                              hipStream_t stream) {
    const float* y1 = (const float*)d_in[0];
    const int total  = in_sizes[0];      // N*D = 64,000,000
    const int total4 = total / 4;        // 16,000,000 float4 groups
    double* acc = (double*)d_ws;

    hipMemsetAsync(acc, 0, sizeof(double), stream);  // d_ws is poisoned 0xAA

    const int block = 256;
    const int grid  = 4096;  // ~15 float4/thread; fills 256 CUs
    mll_reduce_kernel<<<grid, block, 0, stream>>>(y1, acc, total4);
    mll_finalize_kernel<<<1, 1, 0, stream>>>(acc, (float*)d_out,
                                             1.0 / (double)total);
}

// Round 2
// 342.697 us; speedup vs baseline: 1.0519x; 1.0519x over previous
//
#include <hip/hip_runtime.h>

// loss = mean((y1/||y1||_row - y1)^2), y1: [N=4e6, D=16] fp32, yinds unused.
// (w - y)^2 = y^2 * (1/||y|| - 1)^2  -> per-lane local sumsq * (rnorm-1)^2.
// Layout: lane handles one float4; 4 consecutive lanes = one row of 16 floats.
//
// Two-pass reduction: pass 1 writes one double partial per block (NO single-
// address atomic — R1 showed a ~250 us serialized atomic tail), pass 2 (one
// block) sums the partials and writes mean to d_out.

#define GRID1 2048   // 8 blocks/CU x 4 waves = 32 waves/CU: single generation

__global__ __launch_bounds__(256) void mll_pass1_kernel(
    const float* __restrict__ y1, double* __restrict__ partials, int total4) {
    const int tid    = blockIdx.x * blockDim.x + threadIdx.x;
    const int stride = gridDim.x * blockDim.x;  // multiple of 4 -> quad-aligned

    float psum = 0.0f;
    const float4* __restrict__ y4 = reinterpret_cast<const float4*>(y1);
    for (int idx = tid; idx < total4; idx += stride) {
        const float4 v = y4[idx];
        const float local = v.x * v.x + v.y * v.y + v.z * v.z + v.w * v.w;
        // row sum of squares across the 4 lanes of this quad (D=16)
        float row = local;
        row += __shfl_xor(row, 1);
        row += __shfl_xor(row, 2);
        const float c = 1.0f / sqrtf(row) - 1.0f;  // (1/norm - 1)
        psum += local * c * c;                     // sum of (w-y)^2 for 4 elems
    }

    // wave64 butterfly reduction
    #pragma unroll
    for (int off = 32; off > 0; off >>= 1)
        psum += __shfl_xor(psum, off);

    __shared__ float wsum[4];  // 256 threads = 4 waves
    const int lane = threadIdx.x & 63;
    const int wave = threadIdx.x >> 6;
    if (lane == 0) wsum[wave] = psum;
    __syncthreads();
    if (threadIdx.x == 0) {
        partials[blockIdx.x] = (double)(wsum[0] + wsum[1] + wsum[2] + wsum[3]);
    }
}

__global__ __launch_bounds__(256) void mll_pass2_kernel(
    const double* __restrict__ partials, float* __restrict__ out,
    int n_partials, double inv_m) {
    double s = 0.0;
    for (int i = threadIdx.x; i < n_partials; i += 256) s += partials[i];
    #pragma unroll
    for (int off = 32; off > 0; off >>= 1)
        s += __shfl_xor(s, off);
    __shared__ double wsum[4];
    const int lane = threadIdx.x & 63;
    const int wave = threadIdx.x >> 6;
    if (lane == 0) wsum[wave] = s;
    __syncthreads();
    if (threadIdx.x == 0) {
        out[0] = (float)((wsum[0] + wsum[1] + wsum[2] + wsum[3]) * inv_m);
    }
}

extern "C" void kernel_launch(void* const* d_in, const int* in_sizes, int n_in,
                              void* d_out, int out_size, void* d_ws, size_t ws_size,
                              hipStream_t stream) {
    const float* y1 = (const float*)d_in[0];
    const int total  = in_sizes[0];      // N*D = 64,000,000
    const int total4 = total / 4;        // 16,000,000 float4 groups
    double* partials = (double*)d_ws;    // GRID1 doubles, fully overwritten

    mll_pass1_kernel<<<GRID1, 256, 0, stream>>>(y1, partials, total4);
    mll_pass2_kernel<<<1, 256, 0, stream>>>(partials, (float*)d_out,
                                            GRID1, 1.0 / (double)total);
}